// Round 3
// baseline (372.487 us; speedup 1.0000x reference)
//
#include <hip/hip_runtime.h>

// Problem constants (match reference)
#define NC 128
#define NS 2048
#define NX 256
#define NZ 512
#define NB 4                 // B*K
#define NROWS (NX * NZ)      // 131072 output pixels
#define NCOLS (NS * NC)      // 262144 rhs rows

// NOTE: harness passes ALL integer inputs as int32 (csr_rows/csr_cols arrive
// as int*, not int64* — reading them as long long OOB-faults).

// Kernel 1: pack x (B,K,NC,NS) into rhs[j] = float4 over batch, j = s*NC + c.
// rhs[s*128+c][b] = x[b*NC*NS + c*NS + s]
__global__ void pack_rhs_kernel(const float* __restrict__ x,
                                float4* __restrict__ rhs) {
    int j = blockIdx.x * blockDim.x + threadIdx.x;
    if (j >= NCOLS) return;
    int c = j & (NC - 1);
    int s = j >> 7;
    int base = c * NS + s;
    float4 v;
    v.x = x[base];
    v.y = x[base + 1 * NC * NS];
    v.z = x[base + 2 * NC * NS];
    v.w = x[base + 3 * NC * NS];
    rhs[j] = v;
}

// Kernel 2: segment boundaries via binary search on sorted int32 rows.
// row_start[r] = lower_bound(rows, r), r in [0, NROWS].
__global__ void row_bounds_kernel(const int* __restrict__ rows, int nnz,
                                  int* __restrict__ row_start) {
    int r = blockIdx.x * blockDim.x + threadIdx.x;
    if (r > NROWS) return;
    int lo = 0, hi = nnz;
    while (lo < hi) {
        int mid = (lo + hi) >> 1;
        if (rows[mid] < r) lo = mid + 1;
        else hi = mid;
    }
    row_start[r] = lo;
}

// Kernel 3: 8 rows per wave, 8 lanes per row. Segments of consecutive rows
// are contiguous in nnz order (rows sorted), so the wave streams a nearly
// contiguous ~4KB region of vals/cols per pass. vals/cols loaded
// non-temporally to preserve L2 residency of the 4MB rhs gather table.
__global__ void __launch_bounds__(256) spmm_kernel(
        const float* __restrict__ vals,
        const int* __restrict__ cols,
        const int* __restrict__ row_start,
        const float4* __restrict__ rhs,
        float* __restrict__ out) {
    int wid  = (blockIdx.x << 2) + (threadIdx.x >> 6);  // global wave id
    int lane = threadIdx.x & 63;
    int g = lane >> 3;        // row group within wave [0,8)
    int t = lane & 7;         // lane within group

    // lanes 0..8 load the 9 bounds for this wave's 8 rows (coalesced)
    int rb = 0;
    if (lane < 9) rb = row_start[(wid << 3) + lane];
    int s = __shfl(rb, g);
    int e = __shfl(rb, g + 1);

    float4 acc = {0.f, 0.f, 0.f, 0.f};
    for (int i = s + t; i < e; i += 8) {
        float v  = __builtin_nontemporal_load(vals + i);
        int  col = __builtin_nontemporal_load(cols + i);
        float4 rv = rhs[col];            // random 16B gather, L2-resident
        acc.x += v * rv.x;
        acc.y += v * rv.y;
        acc.z += v * rv.z;
        acc.w += v * rv.w;
    }

    // reduce within each 8-lane group
    #pragma unroll
    for (int off = 4; off >= 1; off >>= 1) {
        acc.x += __shfl_xor(acc.x, off, 8);
        acc.y += __shfl_xor(acc.y, off, 8);
        acc.z += __shfl_xor(acc.z, off, 8);
        acc.w += __shfl_xor(acc.w, off, 8);
    }

    if (t < 4) {
        int r = (wid << 3) + g;
        float o = (t == 0) ? acc.x : (t == 1) ? acc.y : (t == 2) ? acc.z : acc.w;
        int ix = r >> 9;          // r / NZ
        int iz = r & (NZ - 1);    // r % NZ
        // out[b, iz, ix] = img_vec[ix*NZ+iz, b],  b = t
        out[t * NROWS + iz * NX + ix] = o;
    }
}

// Fallback (workspace too small): inline bounds + direct gather from x.
__global__ void __launch_bounds__(256) spmm_direct_kernel(
        const float* __restrict__ x,
        const float* __restrict__ vals,
        const int* __restrict__ rows,
        const int* __restrict__ cols,
        int nnz,
        float* __restrict__ out) {
    int r = (blockIdx.x << 2) + (threadIdx.x >> 6);
    int lane = threadIdx.x & 63;
    int start, end;
    {
        int lo = 0, hi = nnz;
        while (lo < hi) { int mid = (lo + hi) >> 1; if (rows[mid] < r) lo = mid + 1; else hi = mid; }
        start = lo;
        hi = nnz;
        int key = r + 1;
        while (lo < hi) { int mid = (lo + hi) >> 1; if (rows[mid] < key) lo = mid + 1; else hi = mid; }
        end = lo;
    }
    float4 acc = {0.f, 0.f, 0.f, 0.f};
    for (int i = start + lane; i < end; i += 64) {
        float v = vals[i];
        int col = cols[i];
        int c = col & (NC - 1);
        int sidx = col >> 7;
        int base = c * NS + sidx;
        acc.x += v * x[base];
        acc.y += v * x[base + 1 * NC * NS];
        acc.z += v * x[base + 2 * NC * NS];
        acc.w += v * x[base + 3 * NC * NS];
    }
    #pragma unroll
    for (int off = 32; off >= 1; off >>= 1) {
        acc.x += __shfl_xor(acc.x, off, 64);
        acc.y += __shfl_xor(acc.y, off, 64);
        acc.z += __shfl_xor(acc.z, off, 64);
        acc.w += __shfl_xor(acc.w, off, 64);
    }
    if (lane < 4) {
        float o = (lane == 0) ? acc.x : (lane == 1) ? acc.y : (lane == 2) ? acc.z : acc.w;
        int ix = r >> 9;
        int iz = r & (NZ - 1);
        out[lane * NROWS + iz * NX + ix] = o;
    }
}

extern "C" void kernel_launch(void* const* d_in, const int* in_sizes, int n_in,
                              void* d_out, int out_size, void* d_ws, size_t ws_size,
                              hipStream_t stream) {
    const float* x        = (const float*)d_in[0];
    const float* csr_vals = (const float*)d_in[1];
    const int*   csr_rows = (const int*)d_in[2];   // harness passes integers as int32
    const int*   csr_cols = (const int*)d_in[3];
    float* out = (float*)d_out;
    int nnz = in_sizes[1];

    size_t need = (size_t)NCOLS * sizeof(float4) + (size_t)(NROWS + 1) * sizeof(int);
    if (ws_size >= need) {
        float4* rhs       = (float4*)d_ws;
        int*    row_start = (int*)((char*)d_ws + (size_t)NCOLS * sizeof(float4));
        pack_rhs_kernel<<<(NCOLS + 255) / 256, 256, 0, stream>>>(x, rhs);
        row_bounds_kernel<<<(NROWS + 1 + 255) / 256, 256, 0, stream>>>(csr_rows, nnz, row_start);
        // 131072 rows / 8 rows-per-wave = 16384 waves = 4096 blocks
        spmm_kernel<<<NROWS / 8 / 4, 256, 0, stream>>>(csr_vals, csr_cols, row_start, rhs, out);
    } else {
        spmm_direct_kernel<<<NROWS / 4, 256, 0, stream>>>(x, csr_vals, csr_rows, csr_cols, nnz, out);
    }
}

// Round 4
// 331.747 us; speedup vs baseline: 1.1228x; 1.1228x over previous
//
#include <hip/hip_runtime.h>

// Problem constants (match reference)
#define NC 128
#define NS 2048
#define NX 256
#define NZ 512
#define NROWS (NX * NZ)      // 131072 output pixels
#define NCOLS (NS * NC)      // 262144 rhs rows
#define WAVE_NNZ 4096        // contiguous nnz per wave (aligned)

// NOTE: harness passes ALL integer inputs as int32 (csr_rows/csr_cols arrive
// as int*, not int64*).
// NOTE (r3 post-mortem): __builtin_nontemporal_load on the vals/cols streams
// REGRESSED (+200MB FETCH, VALUBusy 15->2.8%): partial-line reads refetch the
// same line when retention is disabled. Do not reintroduce.

// Kernel 1: pack x (B,K,NC,NS) into rhs[j] = float4 over batch, j = s*NC + c.
__global__ void pack_rhs_kernel(const float* __restrict__ x,
                                float4* __restrict__ rhs) {
    int j = blockIdx.x * blockDim.x + threadIdx.x;
    if (j >= NCOLS) return;
    int c = j & (NC - 1);
    int s = j >> 7;
    int base = c * NS + s;
    float4 v;
    v.x = x[base];
    v.y = x[base + 1 * NC * NS];
    v.z = x[base + 2 * NC * NS];
    v.w = x[base + 3 * NC * NS];
    rhs[j] = v;
}

// Kernel 2: row_start[r] = lower_bound(rows, r), r in [0, NROWS].
__global__ void row_bounds_kernel(const int* __restrict__ rows, int nnz,
                                  int* __restrict__ row_start) {
    int r = blockIdx.x * blockDim.x + threadIdx.x;
    if (r > NROWS) return;
    int lo = 0, hi = nnz;
    while (lo < hi) {
        int mid = (lo + hi) >> 1;
        if (rows[mid] < r) lo = mid + 1;
        else hi = mid;
    }
    row_start[r] = lo;
}

// Kernel 3: each wave owns a contiguous aligned 4096-nnz block of the stream.
// Per 256-nnz chunk: aligned float4/int4 loads (16B/lane coalesced), 4
// independent rhs gathers per lane, rows recovered by walking the L2-hot
// row_start table, per-row chunk totals via wave-uniform masked butterfly
// reduce, flushed with atomicAdd (out zeroed beforehand).
__global__ void __launch_bounds__(256) spmm_kernel(
        const float* __restrict__ vals,
        const int* __restrict__ cols,
        const int* __restrict__ row_start,
        const float4* __restrict__ rhs,
        float* __restrict__ out,
        int nnz) {
    int wid  = (blockIdx.x << 2) + (threadIdx.x >> 6);
    int lane = threadIdx.x & 63;
    int base = wid * WAVE_NNZ;
    if (base >= nnz) return;

    int e0 = base + lane * 4;
    int eclamp = e0 < nnz ? e0 : (nnz - 1);

    // binary search: largest r with row_start[r] <= eclamp
    int lo = 0, hi = NROWS - 1;
    while (lo < hi) {
        int mid = (lo + hi + 1) >> 1;
        if (row_start[mid] <= eclamp) lo = mid;
        else hi = mid - 1;
    }
    int r = lo;
    int nxt = row_start[r + 1];

    for (int c = 0; c < WAVE_NNZ / 256; ++c) {
        int e = base + c * 256 + lane * 4;
        if (e >= nnz) break;

        float4 v4;
        int4   c4;
        bool full = (e + 3 < nnz);
        if (full) {
            v4 = *(const float4*)(vals + e);   // 16B aligned: e % 4 == 0
            c4 = *(const int4*)(cols + e);
        } else {
            v4 = make_float4(0.f, 0.f, 0.f, 0.f);
            c4 = make_int4(0, 0, 0, 0);
            if (e     < nnz) { v4.x = vals[e];     c4.x = cols[e];     }
            if (e + 1 < nnz) { v4.y = vals[e + 1]; c4.y = cols[e + 1]; }
            if (e + 2 < nnz) { v4.z = vals[e + 2]; c4.z = cols[e + 2]; }
        }

        // 4 independent gathers (L2-resident 4MB table)
        float4 p0 = rhs[c4.x];
        float4 p1 = rhs[c4.y];
        float4 p2 = rhs[c4.z];
        float4 p3 = rhs[c4.w];

        // rows of the 4 elements via forward walk (row_start L1/L2-hot)
        while (e     >= nxt) { ++r; nxt = row_start[r + 1]; }
        int r0 = r;
        while (e + 1 >= nxt) { ++r; nxt = row_start[r + 1]; }
        int r1 = r;
        while (e + 2 >= nxt) { ++r; nxt = row_start[r + 1]; }
        int r2 = r;
        while (e + 3 >= nxt) { ++r; nxt = row_start[r + 1]; }
        int r3 = r;

        p0.x *= v4.x; p0.y *= v4.x; p0.z *= v4.x; p0.w *= v4.x;
        p1.x *= v4.y; p1.y *= v4.y; p1.z *= v4.y; p1.w *= v4.y;
        p2.x *= v4.z; p2.y *= v4.z; p2.z *= v4.z; p2.w *= v4.z;
        p3.x *= v4.w; p3.y *= v4.w; p3.z *= v4.w; p3.w *= v4.w;

        int rfirst = __shfl(r0, 0);
        int rlast  = __shfl(r3, 63);

        for (int rr = rfirst; rr <= rlast; ++rr) {
            float4 a;
            a.x = (r0 == rr ? p0.x : 0.f) + (r1 == rr ? p1.x : 0.f)
                + (r2 == rr ? p2.x : 0.f) + (r3 == rr ? p3.x : 0.f);
            a.y = (r0 == rr ? p0.y : 0.f) + (r1 == rr ? p1.y : 0.f)
                + (r2 == rr ? p2.y : 0.f) + (r3 == rr ? p3.y : 0.f);
            a.z = (r0 == rr ? p0.z : 0.f) + (r1 == rr ? p1.z : 0.f)
                + (r2 == rr ? p2.z : 0.f) + (r3 == rr ? p3.z : 0.f);
            a.w = (r0 == rr ? p0.w : 0.f) + (r1 == rr ? p1.w : 0.f)
                + (r2 == rr ? p2.w : 0.f) + (r3 == rr ? p3.w : 0.f);
            #pragma unroll
            for (int off = 32; off >= 1; off >>= 1) {
                a.x += __shfl_xor(a.x, off, 64);
                a.y += __shfl_xor(a.y, off, 64);
                a.z += __shfl_xor(a.z, off, 64);
                a.w += __shfl_xor(a.w, off, 64);
            }
            if (lane == 0) {
                int ix = rr >> 9;          // rr / NZ
                int iz = rr & (NZ - 1);    // rr % NZ
                int o = iz * NX + ix;
                atomicAdd(&out[0 * NROWS + o], a.x);
                atomicAdd(&out[1 * NROWS + o], a.y);
                atomicAdd(&out[2 * NROWS + o], a.z);
                atomicAdd(&out[3 * NROWS + o], a.w);
            }
        }
    }
}

// Fallback (workspace too small): inline bounds + direct gather from x.
__global__ void __launch_bounds__(256) spmm_direct_kernel(
        const float* __restrict__ x,
        const float* __restrict__ vals,
        const int* __restrict__ rows,
        const int* __restrict__ cols,
        int nnz,
        float* __restrict__ out) {
    int r = (blockIdx.x << 2) + (threadIdx.x >> 6);
    int lane = threadIdx.x & 63;
    int start, end;
    {
        int lo = 0, hi = nnz;
        while (lo < hi) { int mid = (lo + hi) >> 1; if (rows[mid] < r) lo = mid + 1; else hi = mid; }
        start = lo;
        hi = nnz;
        int key = r + 1;
        while (lo < hi) { int mid = (lo + hi) >> 1; if (rows[mid] < key) lo = mid + 1; else hi = mid; }
        end = lo;
    }
    float4 acc = {0.f, 0.f, 0.f, 0.f};
    for (int i = start + lane; i < end; i += 64) {
        float v = vals[i];
        int col = cols[i];
        int c = col & (NC - 1);
        int sidx = col >> 7;
        int b = c * NS + sidx;
        acc.x += v * x[b];
        acc.y += v * x[b + 1 * NC * NS];
        acc.z += v * x[b + 2 * NC * NS];
        acc.w += v * x[b + 3 * NC * NS];
    }
    #pragma unroll
    for (int off = 32; off >= 1; off >>= 1) {
        acc.x += __shfl_xor(acc.x, off, 64);
        acc.y += __shfl_xor(acc.y, off, 64);
        acc.z += __shfl_xor(acc.z, off, 64);
        acc.w += __shfl_xor(acc.w, off, 64);
    }
    if (lane < 4) {
        float o = (lane == 0) ? acc.x : (lane == 1) ? acc.y : (lane == 2) ? acc.z : acc.w;
        int ix = r >> 9;
        int iz = r & (NZ - 1);
        out[lane * NROWS + iz * NX + ix] = o;
    }
}

extern "C" void kernel_launch(void* const* d_in, const int* in_sizes, int n_in,
                              void* d_out, int out_size, void* d_ws, size_t ws_size,
                              hipStream_t stream) {
    const float* x        = (const float*)d_in[0];
    const float* csr_vals = (const float*)d_in[1];
    const int*   csr_rows = (const int*)d_in[2];   // int32 per harness contract
    const int*   csr_cols = (const int*)d_in[3];
    float* out = (float*)d_out;
    int nnz = in_sizes[1];

    size_t need = (size_t)NCOLS * sizeof(float4) + (size_t)(NROWS + 1) * sizeof(int);
    if (ws_size >= need) {
        float4* rhs       = (float4*)d_ws;
        int*    row_start = (int*)((char*)d_ws + (size_t)NCOLS * sizeof(float4));
        hipMemsetAsync(out, 0, (size_t)out_size * sizeof(float), stream);
        pack_rhs_kernel<<<(NCOLS + 255) / 256, 256, 0, stream>>>(x, rhs);
        row_bounds_kernel<<<(NROWS + 1 + 255) / 256, 256, 0, stream>>>(csr_rows, nnz, row_start);
        int nwaves = (nnz + WAVE_NNZ - 1) / WAVE_NNZ;
        int nblocks = (nwaves + 3) / 4;
        spmm_kernel<<<nblocks, 256, 0, stream>>>(csr_vals, csr_cols, row_start, rhs, out, nnz);
    } else {
        spmm_direct_kernel<<<NROWS / 4, 256, 0, stream>>>(x, csr_vals, csr_rows, csr_cols, nnz, out);
    }
}